// Round 9
// baseline (451.583 us; speedup 1.0000x reference)
//
#include <hip/hip_runtime.h>
#include <hip/hip_bf16.h>
#include <cmath>

#define B_DIM 16
#define S_DIM 4096
#define L_DIM 512
#define E_DIM 1024
#define H_DIM 1024

typedef __bf16 bf16;
typedef __attribute__((ext_vector_type(8))) __bf16 bf16x8;
typedef __attribute__((ext_vector_type(4))) __bf16 bf16x4;
typedef __attribute__((ext_vector_type(4))) float f32x4;
typedef __attribute__((ext_vector_type(8))) unsigned short u16x8;

__device__ __forceinline__ void gload_lds16(const void* g, void* l) {
  __builtin_amdgcn_global_load_lds((const __attribute__((address_space(1))) void*)g,
                                   (__attribute__((address_space(3))) void*)l,
                                   16, 0, 0);
}

#define SWZ(o) ((o) ^ ((((o) >> 9) & 1) << 5))

// ---------------- cast f32 -> bf16 (vectorized) ----------------
__global__ void k_cast(const float* __restrict__ in, bf16* __restrict__ out, int n4) {
  int stride = gridDim.x * blockDim.x;
  for (int i = blockIdx.x * blockDim.x + threadIdx.x; i < n4; i += stride) {
    float4 v = reinterpret_cast<const float4*>(in)[i];
    bf16x4 o = { (bf16)v.x, (bf16)v.y, (bf16)v.z, (bf16)v.w };
    reinterpret_cast<bf16x4*>(out)[i] = o;
  }
}

// ---------------- wave-per-row L2-normalize: f32 in -> bf16 out, rows of 1024 ----------------
__global__ __launch_bounds__(256) void k_rownorm_f32(const float* __restrict__ in,
                                                     bf16* __restrict__ out, int nrows) {
  const int wave = (blockIdx.x * 256 + threadIdx.x) >> 6;
  const int lane = threadIdx.x & 63;
  const int nw = (gridDim.x * 256) >> 6;
  for (int r = wave; r < nrows; r += nw) {
    const float4* src = reinterpret_cast<const float4*>(in + (size_t)r * 1024);
    float4 v[4];
    float ss = 0.f;
#pragma unroll
    for (int j = 0; j < 4; ++j) {
      v[j] = src[lane + j * 64];
      ss += v[j].x * v[j].x + v[j].y * v[j].y + v[j].z * v[j].z + v[j].w * v[j].w;
    }
#pragma unroll
    for (int off = 32; off; off >>= 1) ss += __shfl_xor(ss, off);
    const float inv = 1.0f / fmaxf(sqrtf(ss), 1e-12f);
    bf16x4* dst = reinterpret_cast<bf16x4*>(out + (size_t)r * 1024);
#pragma unroll
    for (int j = 0; j < 4; ++j) {
      bf16x4 o = { (bf16)(v[j].x * inv), (bf16)(v[j].y * inv), (bf16)(v[j].z * inv),
                   (bf16)(v[j].w * inv) };
      dst[lane + j * 64] = o;
    }
  }
}

// ---------------- add K2 partials + row L2-normalize -> bf16 lab_n (wave-per-row) ----------------
// P layout [B][2][L][H] f32; row r = b*L + l
__global__ __launch_bounds__(256) void k_rownorm_add(const float* __restrict__ P,
                                                     bf16* __restrict__ out, int nrows) {
  const int wave = (blockIdx.x * 256 + threadIdx.x) >> 6;
  const int lane = threadIdx.x & 63;
  const int nw = (gridDim.x * 256) >> 6;
  for (int r = wave; r < nrows; r += nw) {
    const int b = r >> 9, l = r & 511;
    const float* p0 = P + ((size_t)b * 1024 + l) * 1024;
    const float4* s0 = reinterpret_cast<const float4*>(p0);
    const float4* s1 = reinterpret_cast<const float4*>(p0 + 524288);
    float4 v[4];
    float ss = 0.f;
#pragma unroll
    for (int j = 0; j < 4; ++j) {
      float4 a = s0[lane + j * 64], c = s1[lane + j * 64];
      v[j] = make_float4(a.x + c.x, a.y + c.y, a.z + c.z, a.w + c.w);
      ss += v[j].x * v[j].x + v[j].y * v[j].y + v[j].z * v[j].z + v[j].w * v[j].w;
    }
#pragma unroll
    for (int off = 32; off; off >>= 1) ss += __shfl_xor(ss, off);
    const float inv = 1.0f / fmaxf(sqrtf(ss), 1e-12f);
    bf16x4* dst = reinterpret_cast<bf16x4*>(out + (size_t)r * 1024);
#pragma unroll
    for (int j = 0; j < 4; ++j) {
      bf16x4 o = { (bf16)(v[j].x * inv), (bf16)(v[j].y * inv), (bf16)(v[j].z * inv),
                   (bf16)(v[j].w * inv) };
      dst[lane + j * 64] = o;
    }
  }
}

// ---------------- 64x64-tiled bf16 transpose: in [R][C] -> out [C][R], per batch ----------------
__global__ __launch_bounds__(256) void k_transpose(const bf16* __restrict__ in,
                                                   bf16* __restrict__ out, int R, int C) {
  __shared__ unsigned short tile[64][72];
  const int r0 = blockIdx.x * 64, c0 = blockIdx.y * 64;
  const size_t boff = (size_t)blockIdx.z * (size_t)R * C;
  const unsigned short* src = (const unsigned short*)in + boff;
  unsigned short* dst = (unsigned short*)out + boff;
  const int t = threadIdx.x;
#pragma unroll
  for (int p = 0; p < 2; ++p) {
    int r = p * 32 + (t >> 3);
    int c = (t & 7) * 8;
    u16x8 v = *reinterpret_cast<const u16x8*>(src + (size_t)(r0 + r) * C + c0 + c);
#pragma unroll
    for (int j = 0; j < 8; ++j) tile[r][c + j] = v[j];
  }
  __syncthreads();
#pragma unroll
  for (int p = 0; p < 2; ++p) {
    int cc = p * 32 + (t >> 3);
    int rr = (t & 7) * 8;
    u16x8 o;
#pragma unroll
    for (int j = 0; j < 8; ++j) o[j] = tile[rr + j][cc];
    *reinterpret_cast<u16x8*>(dst + (size_t)(c0 + cc) * R + r0 + rr) = o;
  }
}

// ---------------- 256x256 8-phase NT GEMM (T1+T2+T3+T4+T5) ----------------
// MODE 0: f32 out. MODE 2: bf16 out + fused softmax partials -> part[B][L][16].
template <int MODE, int KSPLIT>
__global__ __launch_bounds__(512, 2) void k_gemm8(
    const bf16* __restrict__ Aall, const bf16* __restrict__ Ball, void* __restrict__ Call,
    const int N, const int ldk, const int Klen, const size_t sA, const size_t sB,
    const size_t sC, const int lg_nbx, const int* __restrict__ mask,
    float2* __restrict__ part) {
  extern __shared__ char lds[];
  const int bid = blockIdx.x, ntot = gridDim.x;
  const int wg = (bid & 7) * (ntot >> 3) + (bid >> 3);
  const int by = wg & 1;
  const int tmp2 = wg >> 1;
  const int bx = tmp2 & ((1 << lg_nbx) - 1);
  const int z = tmp2 >> lg_nbx;
  const int b = z / KSPLIT, ks = z - b * KSPLIT;
  const int koff = ks * Klen;
  const int t = threadIdx.x, wid = t >> 6, lane = t & 63;
  const int wm = wid >> 2, wn = wid & 3;
  const int lane_r = lane & 15;
  const int lane_k = (lane >> 4) * 16;
  const int row0 = by * 256, col0 = bx * 256;
  const bf16* srcA = Aall + (size_t)b * sA + (size_t)row0 * ldk + koff;
  const bf16* srcB = Ball + (size_t)b * sB + (size_t)col0 * ldk + koff;
  const int NKT = Klen >> 6;

  int s_r[2], s_ce[2];
#pragma unroll
  for (int li = 0; li < 2; ++li) {
    int o = li * 8192 + t * 16;
    int so = SWZ(o);
    s_r[li] = so >> 7;
    s_ce[li] = (so & 127) >> 1;
  }

  f32x4 acc[8][4];
#pragma unroll
  for (int i = 0; i < 8; ++i)
#pragma unroll
    for (int j = 0; j < 4; ++j) acc[i][j] = (f32x4){0.f, 0.f, 0.f, 0.f};

  bf16x8 aq[4][2], b0[2][2], b1[2][2];

  auto STAGE = [&](int c, int isB, int h, const bf16* src, int kt_idx) {
#pragma unroll
    for (int li = 0; li < 2; ++li) {
      const bf16* g = src + (size_t)(h * 128 + s_r[li]) * ldk + (kt_idx * 64 + s_ce[li]);
      char* d = lds + c * 65536 + isB * 32768 + h * 16384 + li * 8192 + wid * 1024;
      gload_lds16(g, d);
    }
  };
  auto LDA = [&](int c, int mh) {
#pragma unroll
    for (int mi = 0; mi < 4; ++mi)
#pragma unroll
      for (int kk = 0; kk < 2; ++kk) {
        int rl = (mh * 4 + mi) * 16 + lane_r;
        int o = rl * 128 + lane_k + kk * 64;
        aq[mi][kk] =
            *reinterpret_cast<const bf16x8*>(lds + c * 65536 + wm * 16384 + SWZ(o));
      }
  };
  auto LDB = [&](int c, int nh, bf16x8(&bq)[2][2]) {
#pragma unroll
    for (int ni = 0; ni < 2; ++ni)
#pragma unroll
      for (int kk = 0; kk < 2; ++kk) {
        int rl = (wn & 1) * 64 + (nh * 2 + ni) * 16 + lane_r;
        int o = rl * 128 + lane_k + kk * 64;
        bq[ni][kk] = *reinterpret_cast<const bf16x8*>(lds + c * 65536 + 32768 +
                                                      (wn >> 1) * 16384 + SWZ(o));
      }
  };
  auto MMA = [&](int mh, int nh, bf16x8(&bq)[2][2]) {
#pragma unroll
    for (int mi = 0; mi < 4; ++mi)
#pragma unroll
      for (int ni = 0; ni < 2; ++ni)
#pragma unroll
        for (int kk = 0; kk < 2; ++kk)
          acc[mh * 4 + mi][nh * 2 + ni] = __builtin_amdgcn_mfma_f32_16x16x32_bf16(
              aq[mi][kk], bq[ni][kk], acc[mh * 4 + mi][nh * 2 + ni], 0, 0, 0);
  };

#define GS_BEGIN                                        \
  __builtin_amdgcn_s_barrier();                         \
  asm volatile("s_waitcnt lgkmcnt(0)" ::: "memory");    \
  __builtin_amdgcn_sched_barrier(0);                    \
  __builtin_amdgcn_s_setprio(1);
#define GS_END                                          \
  __builtin_amdgcn_s_setprio(0);                        \
  __builtin_amdgcn_s_barrier();

  STAGE(0, 0, 0, srcA, 0);
  STAGE(0, 1, 0, srcB, 0);
  STAGE(0, 0, 1, srcA, 0);
  STAGE(0, 1, 1, srcB, 0);
  STAGE(1, 0, 0, srcA, 1);
  STAGE(1, 1, 0, srcB, 1);
  STAGE(1, 0, 1, srcA, 1);
  asm volatile("s_waitcnt vmcnt(6)" ::: "memory");
  __builtin_amdgcn_s_barrier();

#pragma unroll 1
  for (int kt = 0; kt < NKT; kt += 2) {
    const bool s2 = kt + 2 < NKT, s3 = kt + 3 < NKT;
    // ph0
    LDA(0, 0);
    LDB(0, 0, b0);
    STAGE(1, 1, 1, srcB, kt + 1);
    GS_BEGIN; MMA(0, 0, b0); GS_END;
    // ph1
    LDB(0, 1, b1);
    GS_BEGIN; MMA(0, 1, b1); GS_END;
    // ph2
    LDA(0, 1);
    if (s2) STAGE(0, 1, 0, srcB, kt + 2);
    GS_BEGIN; MMA(1, 1, b1); GS_END;
    // ph3: wait covers buf1 (kt+1); tail -> vmcnt(0)
    if (s2) {
      STAGE(0, 0, 0, srcA, kt + 2);
      asm volatile("s_waitcnt vmcnt(4)" ::: "memory");
    } else {
      asm volatile("s_waitcnt vmcnt(0)" ::: "memory");
    }
    GS_BEGIN; MMA(1, 0, b0); GS_END;
    // ph4
    LDA(1, 0);
    LDB(1, 0, b0);
    if (s2) STAGE(0, 1, 1, srcB, kt + 2);
    GS_BEGIN; MMA(0, 0, b0); GS_END;
    // ph5
    LDB(1, 1, b1);
    if (s2) STAGE(0, 0, 1, srcA, kt + 2);
    GS_BEGIN; MMA(0, 1, b1); GS_END;
    // ph6
    LDA(1, 1);
    if (s3) STAGE(1, 1, 0, srcB, kt + 3);
    GS_BEGIN; MMA(1, 1, b1); GS_END;
    // ph7: wait covers buf0 (kt+2); tail -> vmcnt(0)
    if (s3) {
      STAGE(1, 0, 0, srcA, kt + 3);
      STAGE(1, 0, 1, srcA, kt + 3);
      asm volatile("s_waitcnt vmcnt(6)" ::: "memory");
    } else {
      asm volatile("s_waitcnt vmcnt(0)" ::: "memory");
    }
    GS_BEGIN; MMA(1, 0, b0); GS_END;
  }
#undef GS_BEGIN
#undef GS_END

  const int rb = row0 + wm * 128 + (lane >> 4) * 4;
  const int cb = col0 + wn * 64 + lane_r;
  if (MODE == 2) {
    bf16* C = (bf16*)Call + (size_t)z * sC;
#pragma unroll
    for (int mf = 0; mf < 8; ++mf)
#pragma unroll
      for (int nf = 0; nf < 4; ++nf)
#pragma unroll
        for (int r = 0; r < 4; ++r)
          C[(size_t)(rb + mf * 16 + r) * N + cb + nf * 16] = (bf16)acc[mf][nf][r];
    bool vld[4];
#pragma unroll
    for (int nf = 0; nf < 4; ++nf)
      vld[nf] = mask[(size_t)b * N + col0 + wn * 64 + nf * 16 + lane_r] != 0;
    float2* smb = reinterpret_cast<float2*>(lds);  // [256 rows][4 wn]
#pragma unroll
    for (int mf = 0; mf < 8; ++mf)
#pragma unroll
      for (int r = 0; r < 4; ++r) {
        float m = -INFINITY;
#pragma unroll
        for (int nf = 0; nf < 4; ++nf)
          if (vld[nf]) m = fmaxf(m, acc[mf][nf][r]);
#pragma unroll
        for (int off = 1; off < 16; off <<= 1) m = fmaxf(m, __shfl_xor(m, off));
        float zz = 0.f;
#pragma unroll
        for (int nf = 0; nf < 4; ++nf)
          if (vld[nf]) zz += __expf(acc[mf][nf][r] - m);
#pragma unroll
        for (int off = 1; off < 16; off <<= 1) zz += __shfl_xor(zz, off);
        if (lane_r == 0)
          smb[(wm * 128 + mf * 16 + (lane >> 4) * 4 + r) * 4 + wn] = make_float2(m, zz);
      }
    __syncthreads();
    if (t < 256) {
      float2 p0 = smb[t * 4 + 0], p1 = smb[t * 4 + 1], p2 = smb[t * 4 + 2],
             p3 = smb[t * 4 + 3];
      float M = fmaxf(fmaxf(p0.x, p1.x), fmaxf(p2.x, p3.x));
      float Z = 0.f;
      if (M != -INFINITY)
        Z = p0.y * __expf(p0.x - M) + p1.y * __expf(p1.x - M) + p2.y * __expf(p2.x - M) +
            p3.y * __expf(p3.x - M);
      part[((size_t)b * L_DIM + row0 + t) * 16 + bx] = make_float2(M, Z);
    }
  } else {
    float* C = (float*)Call + (size_t)z * sC;
#pragma unroll
    for (int mf = 0; mf < 8; ++mf)
#pragma unroll
      for (int nf = 0; nf < 4; ++nf)
#pragma unroll
        for (int r = 0; r < 4; ++r)
          C[(size_t)(rb + mf * 16 + r) * N + cb + nf * 16] = acc[mf][nf][r];
  }
}

// ---------------- combine 16 partials -> (max, 1/Z) per (b,l) ----------------
__global__ void k_sm_comb(const float2* __restrict__ part, float2* __restrict__ mz, int n) {
  int id = blockIdx.x * blockDim.x + threadIdx.x;
  if (id >= n) return;
  float2 p[16];
  float M = -INFINITY;
#pragma unroll
  for (int q = 0; q < 16; ++q) {
    p[q] = part[(size_t)id * 16 + q];
    M = fmaxf(M, p[q].x);
  }
  float Z = 0.f;
  if (M != -INFINITY) {
#pragma unroll
    for (int q = 0; q < 16; ++q)
      if (p[q].x != -INFINITY) Z += p[q].y * __expf(p[q].x - M);
  }
  float rZ = (Z > 0.f) ? 1.0f / Z : 0.f;
  mz[id] = make_float2(M, rZ);
}

// ---------------- softmax write, vectorized: pT bf16 in place + f32 out1 ----------------
__global__ __launch_bounds__(256) void k_sm_write(bf16* __restrict__ GT,
                                                  const int* __restrict__ mask,
                                                  const float2* __restrict__ mz,
                                                  float* __restrict__ out1) {
  __shared__ float tile[64 * 64];
  const int b = blockIdx.z, lt = blockIdx.y, sc = blockIdx.x;
  const int t = threadIdx.x;
  const int l0 = t >> 3;   // 0..31
  const int oct = t & 7;   // s-octet
  const float2 mz0 = mz[(size_t)b * L_DIM + lt * 64 + l0];
  const float2 mz1 = mz[(size_t)b * L_DIM + lt * 64 + l0 + 32];
  const int s_base = sc * 512;
  for (int st = 0; st < 8; ++st) {
    const int s_tile = s_base + st * 64;
    const int4 mk0 =
        *reinterpret_cast<const int4*>(mask + (size_t)b * S_DIM + s_tile + oct * 8);
    const int4 mk1 =
        *reinterpret_cast<const int4*>(mask + (size_t)b * S_DIM + s_tile + oct * 8 + 4);
    const int vm[8] = {mk0.x, mk0.y, mk0.z, mk0.w, mk1.x, mk1.y, mk1.z, mk1.w};
#pragma unroll
    for (int e = 0; e < 2; ++e) {
      const int l = l0 + e * 32;
      const float2 mzv = e ? mz1 : mz0;
      bf16* rp = GT + ((size_t)b * L_DIM + lt * 64 + l) * S_DIM + s_tile + oct * 8;
      const bf16x8 g = *reinterpret_cast<const bf16x8*>(rp);
      bf16x8 pb;
      float pf[8];
#pragma unroll
      for (int j = 0; j < 8; ++j) {
        const float p =
            (vm[j] && mzv.x != -INFINITY) ? __expf((float)g[j] - mzv.x) * mzv.y : 0.f;
        pf[j] = p;
        pb[j] = (bf16)p;
      }
      *reinterpret_cast<bf16x8*>(rp) = pb;
      const int colx = l ^ (oct << 2);
#pragma unroll
      for (int j = 0; j < 8; ++j) tile[(oct * 8 + j) * 64 + colx] = pf[j];
    }
    __syncthreads();
#pragma unroll
    for (int it = 0; it < 4; ++it) {
      const int task = it * 256 + t;
      const int sl = task >> 4, ch = task & 15;
      const int off = sl * 64 + ((ch * 4) ^ ((sl >> 3) << 2));
      const float4 o = *reinterpret_cast<const float4*>(&tile[off]);
      *reinterpret_cast<float4*>(
          &out1[((size_t)b * S_DIM + s_tile + sl) * L_DIM + lt * 64 + ch * 4]) = o;
    }
    __syncthreads();
  }
}

extern "C" void kernel_launch(void* const* d_in, const int* in_sizes, int n_in, void* d_out,
                              int out_size, void* d_ws, size_t ws_size, hipStream_t stream) {
  const float* input_data = (const float*)d_in[0]; // [16,4096,1024]
  const float* label_repr = (const float*)d_in[1]; // [16,512,1024]
  const float* W_proj = (const float*)d_in[2];     // [1024,1024]
  const int* padding = (const int*)d_in[3];        // [16,4096]
  float* out0 = (float*)d_out;                        // output  [16,512,1024]
  float* out1 = out0 + (size_t)B_DIM * L_DIM * H_DIM; // softmax [16,4096,512]

  char* ws = (char*)d_ws;
  bf16* xn = (bf16*)(ws + 0);            // [B][S][H] bf16, 134.2 MB
  bf16* xnT = (bf16*)(ws + 134217728);   // [B][H][S] bf16, 134.2 MB
  bf16* labb = (bf16*)(ws + 268435456);  // label bf16, 16.8 MB
  bf16* Wb = (bf16*)(ws + 285212672);    // W bf16, 2.1 MB
  bf16* lab = (bf16*)(ws + 287309824);   // lab_n bf16, 16.8 MB
  bf16* GT = (bf16*)(ws + 304087040);    // [B][L][S] scores -> pT in place, 67.1 MB
  float2* part = (float2*)(ws + 371195904); // [B][L][16] float2, 1 MB
  float2* mz = (float2*)(ws + 372244480);   // [B][L]
  float* Pk2 = (float*)(ws + 304087040); // K2 partials [B][2][L][H] f32, aliases GT (pre-K3)

  (void)hipFuncSetAttribute((const void*)k_gemm8<0, 2>,
                            hipFuncAttributeMaxDynamicSharedMemorySize, 131072);
  (void)hipFuncSetAttribute((const void*)k_gemm8<0, 1>,
                            hipFuncAttributeMaxDynamicSharedMemorySize, 131072);
  (void)hipFuncSetAttribute((const void*)k_gemm8<2, 1>,
                            hipFuncAttributeMaxDynamicSharedMemorySize, 131072);

  // K0: casts
  k_cast<<<2048, 256, 0, stream>>>(label_repr, labb, (B_DIM * L_DIM * E_DIM) / 4);
  k_cast<<<512, 256, 0, stream>>>(W_proj, Wb, (H_DIM * E_DIM) / 4);
  // K1: normalize x rows -> xn bf16 (wave-per-row, grid-stride)
  k_rownorm_f32<<<2048, 256, 0, stream>>>(input_data, xn, B_DIM * S_DIM);
  // K1b: transpose xn -> xnT
  k_transpose<<<dim3(S_DIM / 64, H_DIM / 64, B_DIM), 256, 0, stream>>>(xn, xnT, S_DIM, H_DIM);
  // K2: partials = label[b] @ W^T (M=L, N=H, K=1024, ksplit 2, 256 blocks) -> f32
  k_gemm8<0, 2><<<256, 512, 131072, stream>>>(labb, Wb, Pk2, H_DIM, E_DIM, 512,
                                              (size_t)L_DIM * E_DIM, 0,
                                              (size_t)L_DIM * H_DIM, 2, nullptr, nullptr);
  // K2b: add partials + normalize rows -> lab_n bf16
  k_rownorm_add<<<512, 256, 0, stream>>>(Pk2, lab, B_DIM * L_DIM);
  // K3: GT[b] = lab_n[b] @ xn[b]^T (M=L, N=S, K=H) -> bf16 + fused sm partials
  k_gemm8<2, 1><<<512, 512, 131072, stream>>>(lab, xn, GT, S_DIM, H_DIM, H_DIM,
                                              (size_t)L_DIM * H_DIM, (size_t)S_DIM * H_DIM,
                                              (size_t)L_DIM * S_DIM, 4, padding, part);
  // K4: combine partials, then write pT + out1 (vectorized)
  k_sm_comb<<<(B_DIM * L_DIM + 255) / 256, 256, 0, stream>>>(part, mz, B_DIM * L_DIM);
  k_sm_write<<<dim3(8, 8, B_DIM), 256, 0, stream>>>(GT, padding, mz, out1);
  // K5: out0[b] = pT[b] @ xnT[b]^T (M=L, N=H, K=4096, no ksplit) -> f32 direct
  k_gemm8<0, 1><<<128, 512, 131072, stream>>>(GT, xnT, out0, H_DIM, S_DIM, S_DIM,
                                              (size_t)L_DIM * S_DIM, (size_t)H_DIM * S_DIM,
                                              (size_t)L_DIM * H_DIM, 2, nullptr, nullptr);
}

// Round 10
// 417.599 us; speedup vs baseline: 1.0814x; 1.0814x over previous
//
#include <hip/hip_runtime.h>
#include <hip/hip_bf16.h>
#include <cmath>

#define B_DIM 16
#define S_DIM 4096
#define L_DIM 512
#define E_DIM 1024
#define H_DIM 1024

typedef __bf16 bf16;
typedef __attribute__((ext_vector_type(8))) __bf16 bf16x8;
typedef __attribute__((ext_vector_type(4))) __bf16 bf16x4;
typedef __attribute__((ext_vector_type(4))) float f32x4;
typedef __attribute__((ext_vector_type(8))) unsigned short u16x8;

__device__ __forceinline__ void gload_lds16(const void* g, void* l) {
  __builtin_amdgcn_global_load_lds((const __attribute__((address_space(1))) void*)g,
                                   (__attribute__((address_space(3))) void*)l,
                                   16, 0, 0);
}

#define SWZ(o) ((o) ^ ((((o) >> 9) & 1) << 5))

// ---------------- fused prep: label cast | W cast | x rownorm (independent ranges) ----------------
__global__ __launch_bounds__(256) void k_prep(const float* __restrict__ label,
                                              bf16* __restrict__ labb,
                                              const float* __restrict__ W,
                                              bf16* __restrict__ Wb,
                                              const float* __restrict__ input,
                                              bf16* __restrict__ xn) {
  const int blk = blockIdx.x;
  if (blk < 512) {
    // label cast: 2,097,152 float4
    for (int i = blk * 256 + threadIdx.x; i < (B_DIM * L_DIM * E_DIM) / 4; i += 512 * 256) {
      float4 v = reinterpret_cast<const float4*>(label)[i];
      bf16x4 o = { (bf16)v.x, (bf16)v.y, (bf16)v.z, (bf16)v.w };
      reinterpret_cast<bf16x4*>(labb)[i] = o;
    }
  } else if (blk < 640) {
    // W cast: 262,144 float4
    for (int i = (blk - 512) * 256 + threadIdx.x; i < (H_DIM * E_DIM) / 4; i += 128 * 256) {
      float4 v = reinterpret_cast<const float4*>(W)[i];
      bf16x4 o = { (bf16)v.x, (bf16)v.y, (bf16)v.z, (bf16)v.w };
      reinterpret_cast<bf16x4*>(Wb)[i] = o;
    }
  } else {
    // wave-per-row L2 normalize of input rows (65536 rows of 1024)
    const int wave = ((blk - 640) * 256 + threadIdx.x) >> 6;
    const int lane = threadIdx.x & 63;
    const int nw = (2048 * 256) >> 6;
    for (int r = wave; r < B_DIM * S_DIM; r += nw) {
      const float4* src = reinterpret_cast<const float4*>(input + (size_t)r * 1024);
      float4 v[4];
      float ss = 0.f;
#pragma unroll
      for (int j = 0; j < 4; ++j) {
        v[j] = src[lane + j * 64];
        ss += v[j].x * v[j].x + v[j].y * v[j].y + v[j].z * v[j].z + v[j].w * v[j].w;
      }
#pragma unroll
      for (int off = 32; off; off >>= 1) ss += __shfl_xor(ss, off);
      const float inv = 1.0f / fmaxf(sqrtf(ss), 1e-12f);
      bf16x4* dst = reinterpret_cast<bf16x4*>(xn + (size_t)r * 1024);
#pragma unroll
      for (int j = 0; j < 4; ++j) {
        bf16x4 o = { (bf16)(v[j].x * inv), (bf16)(v[j].y * inv), (bf16)(v[j].z * inv),
                     (bf16)(v[j].w * inv) };
        dst[lane + j * 64] = o;
      }
    }
  }
}

// ---------------- add K2 partials + row L2-normalize -> bf16 lab_n (wave-per-row) ----------------
__global__ __launch_bounds__(256) void k_rownorm_add(const float* __restrict__ P,
                                                     bf16* __restrict__ out, int nrows) {
  const int wave = (blockIdx.x * 256 + threadIdx.x) >> 6;
  const int lane = threadIdx.x & 63;
  const int nw = (gridDim.x * 256) >> 6;
  for (int r = wave; r < nrows; r += nw) {
    const int b = r >> 9, l = r & 511;
    const float* p0 = P + ((size_t)b * 1024 + l) * 1024;
    const float4* s0 = reinterpret_cast<const float4*>(p0);
    const float4* s1 = reinterpret_cast<const float4*>(p0 + 524288);
    float4 v[4];
    float ss = 0.f;
#pragma unroll
    for (int j = 0; j < 4; ++j) {
      float4 a = s0[lane + j * 64], c = s1[lane + j * 64];
      v[j] = make_float4(a.x + c.x, a.y + c.y, a.z + c.z, a.w + c.w);
      ss += v[j].x * v[j].x + v[j].y * v[j].y + v[j].z * v[j].z + v[j].w * v[j].w;
    }
#pragma unroll
    for (int off = 32; off; off >>= 1) ss += __shfl_xor(ss, off);
    const float inv = 1.0f / fmaxf(sqrtf(ss), 1e-12f);
    bf16x4* dst = reinterpret_cast<bf16x4*>(out + (size_t)r * 1024);
#pragma unroll
    for (int j = 0; j < 4; ++j) {
      bf16x4 o = { (bf16)(v[j].x * inv), (bf16)(v[j].y * inv), (bf16)(v[j].z * inv),
                   (bf16)(v[j].w * inv) };
      dst[lane + j * 64] = o;
    }
  }
}

// ---------------- 64x64-tiled bf16 transpose: in [R][C] -> out [C][R], per batch ----------------
__global__ __launch_bounds__(256) void k_transpose(const bf16* __restrict__ in,
                                                   bf16* __restrict__ out, int R, int C) {
  __shared__ unsigned short tile[64][72];
  const int r0 = blockIdx.x * 64, c0 = blockIdx.y * 64;
  const size_t boff = (size_t)blockIdx.z * (size_t)R * C;
  const unsigned short* src = (const unsigned short*)in + boff;
  unsigned short* dst = (unsigned short*)out + boff;
  const int t = threadIdx.x;
#pragma unroll
  for (int p = 0; p < 2; ++p) {
    int r = p * 32 + (t >> 3);
    int c = (t & 7) * 8;
    u16x8 v = *reinterpret_cast<const u16x8*>(src + (size_t)(r0 + r) * C + c0 + c);
#pragma unroll
    for (int j = 0; j < 8; ++j) tile[r][c + j] = v[j];
  }
  __syncthreads();
#pragma unroll
  for (int p = 0; p < 2; ++p) {
    int cc = p * 32 + (t >> 3);
    int rr = (t & 7) * 8;
    u16x8 o;
#pragma unroll
    for (int j = 0; j < 8; ++j) o[j] = tile[rr + j][cc];
    *reinterpret_cast<u16x8*>(dst + (size_t)(c0 + cc) * R + r0 + rr) = o;
  }
}

// ---------------- add K5 partials -> out0 f32 (LH4 = 2^17 hardcoded) ----------------
__global__ void k_addout(const float* __restrict__ P, float* __restrict__ out, int total4) {
  int stride = gridDim.x * blockDim.x;
  for (int i = blockIdx.x * blockDim.x + threadIdx.x; i < total4; i += stride) {
    int b = i >> 17, rem = i & 131071;
    const float4* p0 = reinterpret_cast<const float4*>(P) + ((size_t)b << 18) + rem;
    float4 a = p0[0], c = p0[131072];
    reinterpret_cast<float4*>(out)[i] = make_float4(a.x + c.x, a.y + c.y, a.z + c.z, a.w + c.w);
  }
}

// ---------------- 256x256 8-phase NT GEMM (T1+T2+T3+T4+T5) ----------------
// MODE 0: f32 out. MODE 2: bf16 out + fused softmax partials -> part[B][L][16].
template <int MODE, int KSPLIT>
__global__ __launch_bounds__(512, 2) void k_gemm8(
    const bf16* __restrict__ Aall, const bf16* __restrict__ Ball, void* __restrict__ Call,
    const int N, const int ldk, const int Klen, const size_t sA, const size_t sB,
    const size_t sC, const int lg_nbx, const int* __restrict__ mask,
    float2* __restrict__ part) {
  extern __shared__ char lds[];
  const int bid = blockIdx.x, ntot = gridDim.x;
  const int wg = (bid & 7) * (ntot >> 3) + (bid >> 3);
  const int by = wg & 1;
  const int tmp2 = wg >> 1;
  const int bx = tmp2 & ((1 << lg_nbx) - 1);
  const int z = tmp2 >> lg_nbx;
  const int b = z / KSPLIT, ks = z - b * KSPLIT;
  const int koff = ks * Klen;
  const int t = threadIdx.x, wid = t >> 6, lane = t & 63;
  const int wm = wid >> 2, wn = wid & 3;
  const int lane_r = lane & 15;
  const int lane_k = (lane >> 4) * 16;
  const int row0 = by * 256, col0 = bx * 256;
  const bf16* srcA = Aall + (size_t)b * sA + (size_t)row0 * ldk + koff;
  const bf16* srcB = Ball + (size_t)b * sB + (size_t)col0 * ldk + koff;
  const int NKT = Klen >> 6;

  int s_r[2], s_ce[2];
#pragma unroll
  for (int li = 0; li < 2; ++li) {
    int o = li * 8192 + t * 16;
    int so = SWZ(o);
    s_r[li] = so >> 7;
    s_ce[li] = (so & 127) >> 1;
  }

  f32x4 acc[8][4];
#pragma unroll
  for (int i = 0; i < 8; ++i)
#pragma unroll
    for (int j = 0; j < 4; ++j) acc[i][j] = (f32x4){0.f, 0.f, 0.f, 0.f};

  bf16x8 aq[4][2], b0[2][2], b1[2][2];

  auto STAGE = [&](int c, int isB, int h, const bf16* src, int kt_idx) {
#pragma unroll
    for (int li = 0; li < 2; ++li) {
      const bf16* g = src + (size_t)(h * 128 + s_r[li]) * ldk + (kt_idx * 64 + s_ce[li]);
      char* d = lds + c * 65536 + isB * 32768 + h * 16384 + li * 8192 + wid * 1024;
      gload_lds16(g, d);
    }
  };
  auto LDA = [&](int c, int mh) {
#pragma unroll
    for (int mi = 0; mi < 4; ++mi)
#pragma unroll
      for (int kk = 0; kk < 2; ++kk) {
        int rl = (mh * 4 + mi) * 16 + lane_r;
        int o = rl * 128 + lane_k + kk * 64;
        aq[mi][kk] =
            *reinterpret_cast<const bf16x8*>(lds + c * 65536 + wm * 16384 + SWZ(o));
      }
  };
  auto LDB = [&](int c, int nh, bf16x8(&bq)[2][2]) {
#pragma unroll
    for (int ni = 0; ni < 2; ++ni)
#pragma unroll
      for (int kk = 0; kk < 2; ++kk) {
        int rl = (wn & 1) * 64 + (nh * 2 + ni) * 16 + lane_r;
        int o = rl * 128 + lane_k + kk * 64;
        bq[ni][kk] = *reinterpret_cast<const bf16x8*>(lds + c * 65536 + 32768 +
                                                      (wn >> 1) * 16384 + SWZ(o));
      }
  };
  auto MMA = [&](int mh, int nh, bf16x8(&bq)[2][2]) {
#pragma unroll
    for (int mi = 0; mi < 4; ++mi)
#pragma unroll
      for (int ni = 0; ni < 2; ++ni)
#pragma unroll
        for (int kk = 0; kk < 2; ++kk)
          acc[mh * 4 + mi][nh * 2 + ni] = __builtin_amdgcn_mfma_f32_16x16x32_bf16(
              aq[mi][kk], bq[ni][kk], acc[mh * 4 + mi][nh * 2 + ni], 0, 0, 0);
  };

#define GS_BEGIN                                        \
  __builtin_amdgcn_s_barrier();                         \
  asm volatile("s_waitcnt lgkmcnt(0)" ::: "memory");    \
  __builtin_amdgcn_sched_barrier(0);                    \
  __builtin_amdgcn_s_setprio(1);
#define GS_END                                          \
  __builtin_amdgcn_s_setprio(0);                        \
  __builtin_amdgcn_s_barrier();

  STAGE(0, 0, 0, srcA, 0);
  STAGE(0, 1, 0, srcB, 0);
  STAGE(0, 0, 1, srcA, 0);
  STAGE(0, 1, 1, srcB, 0);
  STAGE(1, 0, 0, srcA, 1);
  STAGE(1, 1, 0, srcB, 1);
  STAGE(1, 0, 1, srcA, 1);
  asm volatile("s_waitcnt vmcnt(6)" ::: "memory");
  __builtin_amdgcn_s_barrier();

#pragma unroll 1
  for (int kt = 0; kt < NKT; kt += 2) {
    const bool s2 = kt + 2 < NKT, s3 = kt + 3 < NKT;
    // ph0
    LDA(0, 0);
    LDB(0, 0, b0);
    STAGE(1, 1, 1, srcB, kt + 1);
    GS_BEGIN; MMA(0, 0, b0); GS_END;
    // ph1
    LDB(0, 1, b1);
    GS_BEGIN; MMA(0, 1, b1); GS_END;
    // ph2
    LDA(0, 1);
    if (s2) STAGE(0, 1, 0, srcB, kt + 2);
    GS_BEGIN; MMA(1, 1, b1); GS_END;
    // ph3: wait covers buf1 (kt+1); tail -> vmcnt(0)
    if (s2) {
      STAGE(0, 0, 0, srcA, kt + 2);
      asm volatile("s_waitcnt vmcnt(4)" ::: "memory");
    } else {
      asm volatile("s_waitcnt vmcnt(0)" ::: "memory");
    }
    GS_BEGIN; MMA(1, 0, b0); GS_END;
    // ph4
    LDA(1, 0);
    LDB(1, 0, b0);
    if (s2) STAGE(0, 1, 1, srcB, kt + 2);
    GS_BEGIN; MMA(0, 0, b0); GS_END;
    // ph5
    LDB(1, 1, b1);
    if (s2) STAGE(0, 0, 1, srcA, kt + 2);
    GS_BEGIN; MMA(0, 1, b1); GS_END;
    // ph6
    LDA(1, 1);
    if (s3) STAGE(1, 1, 0, srcB, kt + 3);
    GS_BEGIN; MMA(1, 1, b1); GS_END;
    // ph7: wait covers buf0 (kt+2); tail -> vmcnt(0)
    if (s3) {
      STAGE(1, 0, 0, srcA, kt + 3);
      STAGE(1, 0, 1, srcA, kt + 3);
      asm volatile("s_waitcnt vmcnt(6)" ::: "memory");
    } else {
      asm volatile("s_waitcnt vmcnt(0)" ::: "memory");
    }
    GS_BEGIN; MMA(1, 0, b0); GS_END;
  }
#undef GS_BEGIN
#undef GS_END

  const int rb = row0 + wm * 128 + (lane >> 4) * 4;
  const int cb = col0 + wn * 64 + lane_r;
  if (MODE == 2) {
    bf16* C = (bf16*)Call + (size_t)z * sC;
#pragma unroll
    for (int mf = 0; mf < 8; ++mf)
#pragma unroll
      for (int nf = 0; nf < 4; ++nf)
#pragma unroll
        for (int r = 0; r < 4; ++r)
          C[(size_t)(rb + mf * 16 + r) * N + cb + nf * 16] = (bf16)acc[mf][nf][r];
    bool vld[4];
#pragma unroll
    for (int nf = 0; nf < 4; ++nf)
      vld[nf] = mask[(size_t)b * N + col0 + wn * 64 + nf * 16 + lane_r] != 0;
    float2* smb = reinterpret_cast<float2*>(lds);  // [256 rows][4 wn]
#pragma unroll
    for (int mf = 0; mf < 8; ++mf)
#pragma unroll
      for (int r = 0; r < 4; ++r) {
        float m = -INFINITY;
#pragma unroll
        for (int nf = 0; nf < 4; ++nf)
          if (vld[nf]) m = fmaxf(m, acc[mf][nf][r]);
#pragma unroll
        for (int off = 1; off < 16; off <<= 1) m = fmaxf(m, __shfl_xor(m, off));
        float zz = 0.f;
#pragma unroll
        for (int nf = 0; nf < 4; ++nf)
          if (vld[nf]) zz += __expf(acc[mf][nf][r] - m);
#pragma unroll
        for (int off = 1; off < 16; off <<= 1) zz += __shfl_xor(zz, off);
        if (lane_r == 0)
          smb[(wm * 128 + mf * 16 + (lane >> 4) * 4 + r) * 4 + wn] = make_float2(m, zz);
      }
    __syncthreads();
    if (t < 256) {
      float2 p0 = smb[t * 4 + 0], p1 = smb[t * 4 + 1], p2 = smb[t * 4 + 2],
             p3 = smb[t * 4 + 3];
      float M = fmaxf(fmaxf(p0.x, p1.x), fmaxf(p2.x, p3.x));
      float Z = 0.f;
      if (M != -INFINITY)
        Z = p0.y * __expf(p0.x - M) + p1.y * __expf(p1.x - M) + p2.y * __expf(p2.x - M) +
            p3.y * __expf(p3.x - M);
      part[((size_t)b * L_DIM + row0 + t) * 16 + bx] = make_float2(M, Z);
    }
  } else {
    float* C = (float*)Call + (size_t)z * sC;
#pragma unroll
    for (int mf = 0; mf < 8; ++mf)
#pragma unroll
      for (int nf = 0; nf < 4; ++nf)
#pragma unroll
        for (int r = 0; r < 4; ++r)
          C[(size_t)(rb + mf * 16 + r) * N + cb + nf * 16] = acc[mf][nf][r];
  }
}

// ---------------- softmax write (fused combine), vectorized ----------------
// Block start: recompute (max, 1/Z) for its 64 l's from part (redundant per sc,
// deterministic). Then bf16x8 GT read -> exp -> bf16x8 pT store + f32 out1 via
// swizzled LDS transpose.
__global__ __launch_bounds__(256) void k_sm_write(bf16* __restrict__ GT,
                                                  const int* __restrict__ mask,
                                                  const float2* __restrict__ part,
                                                  float* __restrict__ out1) {
  __shared__ float tile[64 * 64];
  __shared__ float2 mzs[64];
  const int b = blockIdx.z, lt = blockIdx.y, sc = blockIdx.x;
  const int t = threadIdx.x;
  if (t < 64) {
    const float2* pp = part + ((size_t)b * L_DIM + lt * 64 + t) * 16;
    float2 p[16];
    float M = -INFINITY;
#pragma unroll
    for (int q = 0; q < 16; ++q) {
      p[q] = pp[q];
      M = fmaxf(M, p[q].x);
    }
    float Z = 0.f;
    if (M != -INFINITY) {
#pragma unroll
      for (int q = 0; q < 16; ++q)
        if (p[q].x != -INFINITY) Z += p[q].y * __expf(p[q].x - M);
    }
    mzs[t] = make_float2(M, (Z > 0.f) ? 1.0f / Z : 0.f);
  }
  __syncthreads();
  const int l0 = t >> 3;  // 0..31
  const int oct = t & 7;  // s-octet
  const float2 mz0 = mzs[l0];
  const float2 mz1 = mzs[l0 + 32];
  const int s_base = sc * 512;
  for (int st = 0; st < 8; ++st) {
    const int s_tile = s_base + st * 64;
    const int4 mk0 =
        *reinterpret_cast<const int4*>(mask + (size_t)b * S_DIM + s_tile + oct * 8);
    const int4 mk1 =
        *reinterpret_cast<const int4*>(mask + (size_t)b * S_DIM + s_tile + oct * 8 + 4);
    const int vm[8] = {mk0.x, mk0.y, mk0.z, mk0.w, mk1.x, mk1.y, mk1.z, mk1.w};
#pragma unroll
    for (int e = 0; e < 2; ++e) {
      const int l = l0 + e * 32;
      const float2 mzv = e ? mz1 : mz0;
      bf16* rp = GT + ((size_t)b * L_DIM + lt * 64 + l) * S_DIM + s_tile + oct * 8;
      const bf16x8 g = *reinterpret_cast<const bf16x8*>(rp);
      bf16x8 pb;
      float pf[8];
#pragma unroll
      for (int j = 0; j < 8; ++j) {
        const float p =
            (vm[j] && mzv.x != -INFINITY) ? __expf((float)g[j] - mzv.x) * mzv.y : 0.f;
        pf[j] = p;
        pb[j] = (bf16)p;
      }
      *reinterpret_cast<bf16x8*>(rp) = pb;
      const int colx = l ^ (oct << 2);
#pragma unroll
      for (int j = 0; j < 8; ++j) tile[(oct * 8 + j) * 64 + colx] = pf[j];
    }
    __syncthreads();
#pragma unroll
    for (int it = 0; it < 4; ++it) {
      const int task = it * 256 + t;
      const int sl = task >> 4, ch = task & 15;
      const int off = sl * 64 + ((ch * 4) ^ ((sl >> 3) << 2));
      const float4 o = *reinterpret_cast<const float4*>(&tile[off]);
      *reinterpret_cast<float4*>(
          &out1[((size_t)b * S_DIM + s_tile + sl) * L_DIM + lt * 64 + ch * 4]) = o;
    }
    __syncthreads();
  }
}

extern "C" void kernel_launch(void* const* d_in, const int* in_sizes, int n_in, void* d_out,
                              int out_size, void* d_ws, size_t ws_size, hipStream_t stream) {
  const float* input_data = (const float*)d_in[0]; // [16,4096,1024]
  const float* label_repr = (const float*)d_in[1]; // [16,512,1024]
  const float* W_proj = (const float*)d_in[2];     // [1024,1024]
  const int* padding = (const int*)d_in[3];        // [16,4096]
  float* out0 = (float*)d_out;                        // output  [16,512,1024]
  float* out1 = out0 + (size_t)B_DIM * L_DIM * H_DIM; // softmax [16,4096,512]

  char* ws = (char*)d_ws;
  bf16* xn = (bf16*)(ws + 0);            // [B][S][H] bf16, 134.2 MB
  bf16* xnT = (bf16*)(ws + 134217728);   // [B][H][S] bf16, 134.2 MB
  bf16* labb = (bf16*)(ws + 268435456);  // label bf16, 16.8 MB
  bf16* Wb = (bf16*)(ws + 285212672);    // W bf16, 2.1 MB
  bf16* lab = (bf16*)(ws + 287309824);   // lab_n bf16, 16.8 MB
  bf16* GT = (bf16*)(ws + 304087040);    // [B][L][S] scores -> pT in place, 67.1 MB
  float2* part = (float2*)(ws + 371195904); // [B][L][16] float2, 1 MB
  float* Pk2 = (float*)(ws + 304087040); // K2 partials [B][2][L][H] f32, aliases GT (pre-K3)
  float* Pk5 = (float*)(ws + 0);         // K5 partials [B][2][L][H] f32, aliases xn (post-K3)

  (void)hipFuncSetAttribute((const void*)k_gemm8<0, 2>,
                            hipFuncAttributeMaxDynamicSharedMemorySize, 131072);
  (void)hipFuncSetAttribute((const void*)k_gemm8<2, 1>,
                            hipFuncAttributeMaxDynamicSharedMemorySize, 131072);

  // K0+K1: casts + x rownorm fused (independent block ranges)
  k_prep<<<2688, 256, 0, stream>>>(label_repr, labb, W_proj, Wb, input_data, xn);
  // K1b: transpose xn -> xnT
  k_transpose<<<dim3(S_DIM / 64, H_DIM / 64, B_DIM), 256, 0, stream>>>(xn, xnT, S_DIM, H_DIM);
  // K2: partials = label[b] @ W^T (M=L, N=H, K=1024, ksplit 2, 256 blocks) -> f32
  k_gemm8<0, 2><<<256, 512, 131072, stream>>>(labb, Wb, Pk2, H_DIM, E_DIM, 512,
                                              (size_t)L_DIM * E_DIM, 0,
                                              (size_t)L_DIM * H_DIM, 2, nullptr, nullptr);
  // K2b: add partials + normalize rows -> lab_n bf16
  k_rownorm_add<<<512, 256, 0, stream>>>(Pk2, lab, B_DIM * L_DIM);
  // K3: GT[b] = lab_n[b] @ xn[b]^T (M=L, N=S, K=H) -> bf16 + fused sm partials
  k_gemm8<2, 1><<<512, 512, 131072, stream>>>(lab, xn, GT, S_DIM, H_DIM, H_DIM,
                                              (size_t)L_DIM * H_DIM, (size_t)S_DIM * H_DIM,
                                              (size_t)L_DIM * S_DIM, 4, padding, part);
  // K4: softmax write (fused combine): pT + out1
  k_sm_write<<<dim3(8, 8, B_DIM), 256, 0, stream>>>(GT, padding, part, out1);
  // K5: partials = pT[b] @ xnT[b]^T (M=L, N=H, K=4096, ksplit 2) -> f32
  k_gemm8<0, 2><<<256, 512, 131072, stream>>>(GT, xnT, Pk5, H_DIM, S_DIM, 2048,
                                              (size_t)L_DIM * S_DIM, (size_t)H_DIM * S_DIM,
                                              (size_t)L_DIM * H_DIM, 2, nullptr, nullptr);
  // K5b: reduce partials -> out0
  k_addout<<<2048, 256, 0, stream>>>(Pk5, out0, (B_DIM * L_DIM * H_DIM) / 4);
}